// Round 7
// baseline (167.629 us; speedup 1.0000x reference)
//
#include <hip/hip_runtime.h>
#include <cstdint>

#define PPB 8      // points per block
#define ROW 351    // 32 + 32*4*2 + 3 + 3*10*2
#define CH 32

#define INV2PI 0.15915494f   // revolutions scale for v_sin/v_cos

__global__ __launch_bounds__(256)
void embed_voxel_kernel(const float* __restrict__ xyz,
                        const float* __restrict__ table,
                        const int*   __restrict__ vmap,
                        const float* __restrict__ voff,
                        const float* __restrict__ vsize,
                        const int*   __restrict__ vshape,
                        float* __restrict__ out,
                        int npts)
{
    __shared__ float swt[PPB * 8];                    // corner weights
    __shared__ int   sidx[PPB * 8];                   // corner table indices

    const int tid = threadIdx.x;

    // ---- Phase A: one thread per (point,corner) — 64 threads ----
    if (tid < PPB * 8) {
        const int p = tid >> 3, k = tid & 7;
        const int sx = vshape[0], sy = vshape[1], sz = vshape[2];
        const float vs = vsize[0];
        const size_t n3 = ((size_t)blockIdx.x * PPB + p) * 3;
        float w = 1.0f;
        bool valid = true;
        int qq[3];
        #pragma unroll
        for (int d = 0; d < 3; ++d) {
            const float v = (xyz[n3 + d] + voff[d]) / vs;  // IEEE divide, matches ref
            const float fl = floorf(v);
            const float fr = v - fl;
            const int b = (k >> (2 - d)) & 1;
            const int qd = (int)fl + b;
            w *= b ? fr : 1.0f - fr;
            const int sd = (d == 0) ? sx : (d == 1) ? sy : sz;
            valid = valid && (qd >= 0) && (qd < sd);
            qq[d] = qd;
        }
        const int cqx = valid ? qq[0] : 0;
        const int cqy = valid ? qq[1] : 0;
        const int cqz = valid ? qq[2] : 0;
        const int id = vmap[((size_t)cqx * sy + cqy) * sz + cqz];
        swt[tid]  = (valid && id >= 0) ? w : 0.0f;
        sidx[tid] = (id >= 0) ? id : 0;
    }
    __syncthreads();

    // ---- Phase B: gather + weighted sum + DIRECT non-temporal stores ----
    const int p  = tid >> 5;
    const int ch = tid & 31;
    const int n  = blockIdx.x * PPB + p;
    const size_t n3 = (size_t)n * 3;

    float acc = 0.0f;
    #pragma unroll
    for (int k = 0; k < 8; ++k) {
        const unsigned off = (unsigned)sidx[p * 8 + k] * CH + ch;  // 32-bit addressing
        acc = fmaf(swt[p * 8 + k], table[off], acc);
    }

    float* r = out + (size_t)n * ROW;

    // voxel_ftr channels [0..31]
    __builtin_nontemporal_store(acc, r + ch);
    // inst = channels 24..31
    if (ch >= 24)
        __builtin_nontemporal_store(acc, out + (size_t)npts * ROW + (size_t)n * 8 + (ch - 24));

    // posenc(voxel_ftr, 4): index = 32 + f*64 + s*32 + ch
    #pragma unroll
    for (int f = 0; f < 4; ++f) {
        const float t = acc * ((float)(1 << f) * INV2PI);
        __builtin_nontemporal_store(__builtin_amdgcn_sinf(t), r + 32 + f * 64 + ch);
        __builtin_nontemporal_store(__builtin_amdgcn_cosf(t), r + 32 + f * 64 + 32 + ch);
    }

    // posenc(xyz, 10): raw xyz at 288+d, sin at 291+f*6+d, cos at 291+f*6+3+d
    if (ch < 3)
        __builtin_nontemporal_store(xyz[n3 + ch], r + 288 + ch);
    if (ch < 30) {
        const int f = ch / 3, d = ch % 3;
        const float t = xyz[n3 + d] * ((float)(1 << f) * INV2PI);
        __builtin_nontemporal_store(__builtin_amdgcn_sinf(t), r + 291 + f * 6 + d);
        __builtin_nontemporal_store(__builtin_amdgcn_cosf(t), r + 291 + f * 6 + 3 + d);
    }
}

extern "C" void kernel_launch(void* const* d_in, const int* in_sizes, int n_in,
                              void* d_out, int out_size, void* d_ws, size_t ws_size,
                              hipStream_t stream) {
    const float* xyz    = (const float*)d_in[0];
    const float* table  = (const float*)d_in[1];
    const int*   vmap   = (const int*)d_in[2];
    const float* voff   = (const float*)d_in[3];
    const float* vsize  = (const float*)d_in[4];
    const int*   vshape = (const int*)d_in[5];
    float* out = (float*)d_out;

    const int npts = in_sizes[0] / 3;      // 262144
    const int blocks = npts / PPB;         // 32768
    embed_voxel_kernel<<<blocks, 256, 0, stream>>>(xyz, table, vmap, voff, vsize,
                                                   vshape, out, npts);
}

// Round 8
// 97.976 us; speedup vs baseline: 1.7109x; 1.7109x over previous
//
#include <hip/hip_runtime.h>
#include <cstdint>

#define PPB 16     // points per block
#define ROW 351    // 32 + 32*4*2 + 3 + 3*10*2
#define CH 32

typedef float f32x4 __attribute__((ext_vector_type(4)));

#define INV2PI 0.15915494f   // revolutions scale for v_sin/v_cos

__global__ __launch_bounds__(512)
void embed_voxel_kernel(const float* __restrict__ xyz,
                        const float* __restrict__ table,
                        const int*   __restrict__ vmap,
                        const float* __restrict__ voff,
                        const float* __restrict__ vsize,
                        const int*   __restrict__ vshape,
                        float* __restrict__ out,
                        int npts)
{
    __shared__ __align__(16) float rows[PPB * ROW];   // 22464 B
    __shared__ __align__(16) float inst[PPB * 8];     // 512 B
    __shared__ float swt[PPB * 8];                    // corner weights
    __shared__ int   sidx[PPB * 8];                   // corner table indices

    const int tid = threadIdx.x;
    const int p   = tid >> 5;            // point within block (0..15)
    const int ch  = tid & 31;            // channel
    const int n   = blockIdx.x * PPB + p;
    const size_t n3 = (size_t)n * 3;

    float* r = rows + p * ROW;

    // ---- Pre-barrier: gather-INDEPENDENT xyz posenc (overlaps phase-A latency) ----
    // raw xyz at 288+d, sin at 291+f*6+d, cos at 291+f*6+3+d
    if (ch < 3) r[288 + ch] = xyz[n3 + ch];
    if (ch < 30) {
        const int f = ch / 3, d = ch % 3;
        const float t = xyz[n3 + d] * ((float)(1 << f) * INV2PI);
        r[291 + f * 6 + d]     = __builtin_amdgcn_sinf(t);
        r[291 + f * 6 + 3 + d] = __builtin_amdgcn_cosf(t);
    }

    // ---- Phase A: one thread per (point,corner) — 128 threads ----
    if (tid < PPB * 8) {
        const int pa = tid >> 3, k = tid & 7;
        const int sx = vshape[0], sy = vshape[1], sz = vshape[2];
        const float vs = vsize[0];
        const size_t a3 = ((size_t)blockIdx.x * PPB + pa) * 3;
        float w = 1.0f;
        bool valid = true;
        int qq[3];
        #pragma unroll
        for (int d = 0; d < 3; ++d) {
            const float v = (xyz[a3 + d] + voff[d]) / vs;  // IEEE divide, matches ref
            const float fl = floorf(v);
            const float fr = v - fl;
            const int b = (k >> (2 - d)) & 1;
            const int qd = (int)fl + b;
            w *= b ? fr : 1.0f - fr;
            const int sd = (d == 0) ? sx : (d == 1) ? sy : sz;
            valid = valid && (qd >= 0) && (qd < sd);
            qq[d] = qd;
        }
        const int cqx = valid ? qq[0] : 0;
        const int cqy = valid ? qq[1] : 0;
        const int cqz = valid ? qq[2] : 0;
        const int id = vmap[((size_t)cqx * sy + cqy) * sz + cqz];
        swt[tid]  = (valid && id >= 0) ? w : 0.0f;
        sidx[tid] = (id >= 0) ? id : 0;
    }
    __syncthreads();

    // ---- Phase B: gather + weighted sum, one thread per (point,channel) ----
    float acc = 0.0f;
    #pragma unroll
    for (int k = 0; k < 8; ++k) {
        const unsigned off = (unsigned)sidx[p * 8 + k] * CH + ch;  // 32-bit addressing
        acc = fmaf(swt[p * 8 + k], table[off], acc);
    }

    r[ch] = acc;                                   // voxel_ftr channels [0..31]
    if (ch >= 24) inst[p * 8 + (ch - 24)] = acc;   // inst = channels 24..31

    // posenc(voxel_ftr, 4): index = 32 + f*64 + s*32 + ch
    #pragma unroll
    for (int f = 0; f < 4; ++f) {
        const float t = acc * ((float)(1 << f) * INV2PI);
        r[32 + f * 64 + ch]      = __builtin_amdgcn_sinf(t);
        r[32 + f * 64 + 32 + ch] = __builtin_amdgcn_cosf(t);
    }

    __syncthreads();

    // ---- coalesced non-temporal write-out ----
    // out0: this block's 16 rows = 5616 contiguous floats = 1404 float4
    {
        f32x4* dst = (f32x4*)(out + (size_t)blockIdx.x * (PPB * ROW));
        const f32x4* src = (const f32x4*)rows;
        for (int i = tid; i < (PPB * ROW) / 4; i += 512)
            __builtin_nontemporal_store(src[i], &dst[i]);
    }
    // out1: 128 contiguous floats = 32 float4
    if (tid < 32) {
        f32x4* dst = (f32x4*)(out + (size_t)npts * ROW + (size_t)blockIdx.x * (PPB * 8));
        __builtin_nontemporal_store(((const f32x4*)inst)[tid], &dst[tid]);
    }
}

extern "C" void kernel_launch(void* const* d_in, const int* in_sizes, int n_in,
                              void* d_out, int out_size, void* d_ws, size_t ws_size,
                              hipStream_t stream) {
    const float* xyz    = (const float*)d_in[0];
    const float* table  = (const float*)d_in[1];
    const int*   vmap   = (const int*)d_in[2];
    const float* voff   = (const float*)d_in[3];
    const float* vsize  = (const float*)d_in[4];
    const int*   vshape = (const int*)d_in[5];
    float* out = (float*)d_out;

    const int npts = in_sizes[0] / 3;      // 262144
    const int blocks = npts / PPB;         // 16384
    embed_voxel_kernel<<<blocks, 512, 0, stream>>>(xyz, table, vmap, voff, vsize,
                                                   vshape, out, npts);
}